// Round 1
// baseline (5516.648 us; speedup 1.0000x reference)
//
#include <hip/hip_runtime.h>
#include <math.h>

#define B_ 8
#define L_ 256
#define N_ 22
#define C_ 128
#define H_ 8
#define DK_ 16
#define DFF_ 512
#define NL_ 6
#define MTOK (B_*L_*N_)   // 45056

__device__ __forceinline__ float wave_sum(float v){
#pragma unroll
  for (int i = 32; i >= 1; i >>= 1) v += __shfl_xor(v, i, 64);
  return v;
}

__device__ __forceinline__ float mishf(float v){
  return v * tanhf(log1pf(expf(v)));
}

// ---------------- positional-encoder kernel: out = x + LN(x + pe) ----------------
__global__ __launch_bounds__(256) void pe_kernel(
    const float* __restrict__ x, const float* __restrict__ g,
    const float* __restrict__ b, float* __restrict__ out)
{
  int row  = (blockIdx.x * 256 + threadIdx.x) >> 6;   // token index
  int lane = threadIdx.x & 63;
  if (row >= MTOK) return;
  int bl = row / N_;            // b*L + l
  int l  = bl & (L_ - 1);
  const float* xr = x + (size_t)row * C_;
  float x0 = xr[lane], x1 = xr[lane + 64];
  int c0 = lane, c1 = lane + 64;
  const float LOG1E4 = 9.210340371976184f;
  float e0 = expf(LOG1E4 * (-2.0f * (float)c0 / 128.0f));
  float e1 = expf(LOG1E4 * (-2.0f * (float)c1 / 128.0f));
  float a0 = (float)l * e0, a1 = (float)l * e1;
  float pe0 = (c0 & 1) ? cosf(a0) : sinf(a0);
  float pe1 = (c1 & 1) ? cosf(a1) : sinf(a1);
  float t0 = x0 + pe0, t1 = x1 + pe1;
  float mean = wave_sum(t0 + t1) * (1.0f/128.0f);
  float d0 = t0 - mean, d1 = t1 - mean;
  float var = wave_sum(d0*d0 + d1*d1) * (1.0f/128.0f);
  float inv = rsqrtf(var + 1e-5f);
  float* orow = out + (size_t)row * C_;
  orow[c0] = x0 + d0 * inv * g[c0] + b[c0];
  orow[c1] = x1 + d1 * inv * g[c1] + b[c1];
}

// ---------------- plain LayerNorm over C=128, wave per row ----------------
__global__ __launch_bounds__(256) void ln_kernel(
    const float* __restrict__ in, const float* __restrict__ g,
    const float* __restrict__ b, float* __restrict__ out)
{
  int row  = (blockIdx.x * 256 + threadIdx.x) >> 6;
  int lane = threadIdx.x & 63;
  if (row >= MTOK) return;
  const float* ir = in + (size_t)row * C_;
  float t0 = ir[lane], t1 = ir[lane + 64];
  float mean = wave_sum(t0 + t1) * (1.0f/128.0f);
  float d0 = t0 - mean, d1 = t1 - mean;
  float var = wave_sum(d0*d0 + d1*d1) * (1.0f/128.0f);
  float inv = rsqrtf(var + 1e-5f);
  float* orow = out + (size_t)row * C_;
  orow[lane]      = d0 * inv * g[lane]      + b[lane];
  orow[lane + 64] = d1 * inv * g[lane + 64] + b[lane + 64];
}

// ---------------- fp32 GEMM: C[m,n] = sum_k A[m,k]*Bw[n,k] (+bias, epi) ----------
// A [M,K] row-major (stride K), Bw [Ntot,K] row-major, tile 128x128, BK=16,
// 8x8 microtile per thread (256 threads). EPI: 0=+bias, 1=mish(+bias), 2=res+bias.
template<int EPI>
__global__ __launch_bounds__(256) void gemm_kernel(
    const float* __restrict__ A, const float* __restrict__ Bw,
    const float* __restrict__ bias, const float* __restrict__ res,
    float* __restrict__ Cout, int K, int Ntot)
{
  __shared__ float sA[16][132];
  __shared__ float sB[16][132];
  const int t  = threadIdx.x;
  const int bm = blockIdx.x * 128;
  const int bn = blockIdx.y * 128;
  const int r  = t >> 2;          // 0..63
  const int c4 = (t & 3) * 4;     // 0,4,8,12
  const int ty = t >> 4;          // 0..15 (row group)
  const int tx = t & 15;          // 0..15 (col group)
  const float* Ap = A  + (size_t)(bm + r) * K + c4;
  const float* Bp = Bw + (size_t)(bn + r) * K + c4;

  float acc[8][8];
#pragma unroll
  for (int i = 0; i < 8; ++i)
#pragma unroll
    for (int j = 0; j < 8; ++j) acc[i][j] = 0.0f;

  for (int k0 = 0; k0 < K; k0 += 16) {
    float4 a0 = *(const float4*)(Ap + k0);
    float4 a1 = *(const float4*)(Ap + k0 + (size_t)64 * K);
    float4 b0 = *(const float4*)(Bp + k0);
    float4 b1 = *(const float4*)(Bp + k0 + (size_t)64 * K);
    sA[c4+0][r] = a0.x; sA[c4+1][r] = a0.y; sA[c4+2][r] = a0.z; sA[c4+3][r] = a0.w;
    sA[c4+0][r+64] = a1.x; sA[c4+1][r+64] = a1.y; sA[c4+2][r+64] = a1.z; sA[c4+3][r+64] = a1.w;
    sB[c4+0][r] = b0.x; sB[c4+1][r] = b0.y; sB[c4+2][r] = b0.z; sB[c4+3][r] = b0.w;
    sB[c4+0][r+64] = b1.x; sB[c4+1][r+64] = b1.y; sB[c4+2][r+64] = b1.z; sB[c4+3][r+64] = b1.w;
    __syncthreads();
#pragma unroll
    for (int kk = 0; kk < 16; ++kk) {
      float av[8], bv[8];
      *(float4*)&av[0] = *(const float4*)&sA[kk][ty*8];
      *(float4*)&av[4] = *(const float4*)&sA[kk][ty*8+4];
      *(float4*)&bv[0] = *(const float4*)&sB[kk][tx*8];
      *(float4*)&bv[4] = *(const float4*)&sB[kk][tx*8+4];
#pragma unroll
      for (int i = 0; i < 8; ++i)
#pragma unroll
        for (int j = 0; j < 8; ++j)
          acc[i][j] = fmaf(av[i], bv[j], acc[i][j]);
    }
    __syncthreads();
  }

#pragma unroll
  for (int i = 0; i < 8; ++i) {
    int m = bm + ty*8 + i;
    size_t base = (size_t)m * Ntot + bn + tx*8;
#pragma unroll
    for (int jh = 0; jh < 2; ++jh) {
      float4 o;
      float* ov = (float*)&o;
#pragma unroll
      for (int j2 = 0; j2 < 4; ++j2) {
        int j = jh*4 + j2;
        float v = acc[i][j] + bias[bn + tx*8 + j];
        if (EPI == 1) v = mishf(v);
        ov[j2] = v;
      }
      if (EPI == 2) {
        float4 rv = *(const float4*)(res + base + jh*4);
        o.x += rv.x; o.y += rv.y; o.z += rv.z; o.w += rv.w;
      }
      *(float4*)(Cout + base + jh*4) = o;
    }
  }
}

// ---------------- attention over nodes, block per (b,l), scatter-scrambled out ---
// scores[n,m] = Q[n]·K[m] / 4; a[n,d] = sum_m softmax(scores)[n,m] V[m,d]
// scramble: out[b,l2,n2] = a[b,l,n] with n*L + l == l2*N + n2
__global__ __launch_bounds__(256) void attn_kernel(
    const float* __restrict__ q, const float* __restrict__ k,
    const float* __restrict__ v, float* __restrict__ out)
{
  __shared__ float Ks[N_ * C_];
  __shared__ float Vs[N_ * C_];
  int bl = blockIdx.x;            // b*L + l
  int b  = bl >> 8;
  int l  = bl & (L_ - 1);
  size_t mb = (size_t)bl * N_;    // base token
  for (int i = threadIdx.x; i < N_ * C_; i += 256) {
    Ks[i] = k[mb * C_ + i];
    Vs[i] = v[mb * C_ + i];
  }
  __syncthreads();
  int h  = threadIdx.x >> 5;      // 0..7
  int nq = threadIdx.x & 31;
  if (nq >= N_) return;
  float qr[DK_];
  const float* qp = q + (mb + nq) * C_ + h * DK_;
#pragma unroll
  for (int d = 0; d < DK_; ++d) qr[d] = qp[d];
  float sc[N_];
#pragma unroll
  for (int m = 0; m < N_; ++m) {
    float s = 0.0f;
#pragma unroll
    for (int d = 0; d < DK_; ++d) s = fmaf(qr[d], Ks[m*C_ + h*DK_ + d], s);
    sc[m] = s * 0.25f;            // 1/sqrt(16)
  }
  float mx = -1e30f;
#pragma unroll
  for (int m = 0; m < N_; ++m) mx = fmaxf(mx, sc[m]);
  float sum = 0.0f;
#pragma unroll
  for (int m = 0; m < N_; ++m) { sc[m] = expf(sc[m] - mx); sum += sc[m]; }
  float rs = 1.0f / sum;
  float o[DK_];
#pragma unroll
  for (int d = 0; d < DK_; ++d) o[d] = 0.0f;
#pragma unroll
  for (int m = 0; m < N_; ++m)
#pragma unroll
    for (int d = 0; d < DK_; ++d) o[d] = fmaf(sc[m], Vs[m*C_ + h*DK_ + d], o[d]);
  // scramble scatter
  int flat = nq * L_ + l;
  int l2 = flat / N_;
  int n2 = flat - l2 * N_;
  float* op = out + ((size_t)((b * L_ + l2) * N_ + n2)) * C_ + h * DK_;
#pragma unroll
  for (int d = 0; d < DK_; ++d) op[d] = o[d] * rs;
}

extern "C" void kernel_launch(void* const* d_in, const int* in_sizes, int n_in,
                              void* d_out, int out_size, void* d_ws, size_t ws_size,
                              hipStream_t stream) {
  const float* x    = (const float*)d_in[0];
  const float* Wq   = (const float*)d_in[1];
  const float* bq   = (const float*)d_in[2];
  const float* Wk   = (const float*)d_in[3];
  const float* bk   = (const float*)d_in[4];
  const float* Wv   = (const float*)d_in[5];
  const float* bv   = (const float*)d_in[6];
  const float* Wo   = (const float*)d_in[7];
  const float* bo   = (const float*)d_in[8];
  const float* W1   = (const float*)d_in[9];
  const float* bf1  = (const float*)d_in[10];
  const float* W2   = (const float*)d_in[11];
  const float* bf2  = (const float*)d_in[12];
  const float* ln1g = (const float*)d_in[13];
  const float* ln1b = (const float*)d_in[14];
  const float* lnAg = (const float*)d_in[15];
  const float* lnAb = (const float*)d_in[16];
  const float* lnFg = (const float*)d_in[17];
  const float* lnFb = (const float*)d_in[18];
  const float* peg  = (const float*)d_in[19];
  const float* peb  = (const float*)d_in[20];

  float* out = (float*)d_out;
  float* ws  = (float*)d_ws;
  const size_t U = (size_t)MTOK * C_;   // 5,767,168 floats
  float* y   = ws;            // LN1 output (residual base)
  float* qb  = ws + 1*U;      // Q  / later s2 (post-Wo)
  float* kb  = ws + 2*U;      // K  / later z
  float* vb  = ws + 3*U;      // V  / later u2
  float* sb  = ws + 4*U;      // scrambled attn out / later u4
  float* mid = ws + 5*U;      // FF hidden, one half-chunk (2U floats)

  dim3 blk(256);
  const int lnGrid = MTOK / 4;          // 11264 blocks, 4 rows each
  const int MH = MTOK / 2;              // 22528 tokens per FF chunk

  pe_kernel<<<lnGrid, blk, 0, stream>>>(x, peg, peb, out);

  for (int li = 0; li < NL_; ++li) {
    const float* Wq_l = Wq + (size_t)li * H_ * DK_ * C_;
    const float* Wk_l = Wk + (size_t)li * H_ * DK_ * C_;
    const float* Wv_l = Wv + (size_t)li * H_ * DK_ * C_;
    const float* bq_l = bq + (size_t)li * H_ * DK_;
    const float* bk_l = bk + (size_t)li * H_ * DK_;
    const float* bv_l = bv + (size_t)li * H_ * DK_;
    const float* Wo_l = Wo + (size_t)li * C_ * (H_ * DK_);
    const float* bo_l = bo + (size_t)li * C_;
    const float* W1_l = W1 + (size_t)li * DFF_ * C_;
    const float* b1_l = bf1 + (size_t)li * DFF_;
    const float* W2_l = W2 + (size_t)li * C_ * DFF_;
    const float* b2_l = bf2 + (size_t)li * C_;
    const float* g1 = ln1g + (size_t)li * C_; const float* bb1 = ln1b + (size_t)li * C_;
    const float* gA = lnAg + (size_t)li * C_; const float* bA  = lnAb + (size_t)li * C_;
    const float* gF = lnFg + (size_t)li * C_; const float* bF  = lnFb + (size_t)li * C_;

    // y = LN1(h)
    ln_kernel<<<lnGrid, blk, 0, stream>>>(out, g1, bb1, y);

    // Q,K,V = y @ W^T + b
    dim3 gqkv(MTOK/128, 1);
    gemm_kernel<0><<<gqkv, blk, 0, stream>>>(y, Wq_l, bq_l, nullptr, qb, C_, C_);
    gemm_kernel<0><<<gqkv, blk, 0, stream>>>(y, Wk_l, bk_l, nullptr, kb, C_, C_);
    gemm_kernel<0><<<gqkv, blk, 0, stream>>>(y, Wv_l, bv_l, nullptr, vb, C_, C_);

    // attention + head scramble -> sb
    attn_kernel<<<B_*L_, blk, 0, stream>>>(qb, kb, vb, sb);

    // s2 = y + sb @ Wo^T + bo   (into qb)
    gemm_kernel<2><<<gqkv, blk, 0, stream>>>(sb, Wo_l, bo_l, y, qb, C_, C_);
    // z = LN_A(s2)  (into kb)
    ln_kernel<<<lnGrid, blk, 0, stream>>>(qb, gA, bA, kb);

    // FF block #1: u2 = z + mish(z@W1^T+b1)@W2^T+b2  (into vb), u3 = LN_F(u2) (into y)
    for (int ch = 0; ch < 2; ++ch) {
      const float* zin = kb + (size_t)ch * MH * C_;
      float* u2 = vb + (size_t)ch * MH * C_;
      dim3 gf1(MH/128, DFF_/128);
      gemm_kernel<1><<<gf1, blk, 0, stream>>>(zin, W1_l, b1_l, nullptr, mid, C_, DFF_);
      dim3 gf2(MH/128, 1);
      gemm_kernel<2><<<gf2, blk, 0, stream>>>(mid, W2_l, b2_l, zin, u2, DFF_, C_);
    }
    ln_kernel<<<lnGrid, blk, 0, stream>>>(vb, gF, bF, y);

    // FF block #2: u4 = u3 + mish(u3@W1^T+b1)@W2^T+b2 (into sb), h_next = LN_F(u4) -> out
    for (int ch = 0; ch < 2; ++ch) {
      const float* uin = y + (size_t)ch * MH * C_;
      float* u4 = sb + (size_t)ch * MH * C_;
      dim3 gf1(MH/128, DFF_/128);
      gemm_kernel<1><<<gf1, blk, 0, stream>>>(uin, W1_l, b1_l, nullptr, mid, C_, DFF_);
      dim3 gf2(MH/128, 1);
      gemm_kernel<2><<<gf2, blk, 0, stream>>>(mid, W2_l, b2_l, uin, u4, DFF_, C_);
    }
    ln_kernel<<<lnGrid, blk, 0, stream>>>(sb, gF, bF, out);
  }
  (void)in_sizes; (void)n_in; (void)out_size; (void)ws_size;
}

// Round 2
// 3038.010 us; speedup vs baseline: 1.8159x; 1.8159x over previous
//
#include <hip/hip_runtime.h>
#include <math.h>

#define B_ 8
#define L_ 256
#define N_ 22
#define C_ 128
#define H_ 8
#define DK_ 16
#define DFF_ 512
#define NL_ 6
#define MTOK (B_*L_*N_)   // 45056

typedef __bf16 bf16x8 __attribute__((ext_vector_type(8)));
typedef float  f32x4  __attribute__((ext_vector_type(4)));

__device__ __forceinline__ float wave_sum(float v){
#pragma unroll
  for (int i = 32; i >= 1; i >>= 1) v += __shfl_xor(v, i, 64);
  return v;
}

__device__ __forceinline__ float mishf(float v){
  return v * tanhf(log1pf(expf(v)));
}

// ---------------- positional-encoder kernel: out = x + LN(x + pe) ----------------
__global__ __launch_bounds__(256) void pe_kernel(
    const float* __restrict__ x, const float* __restrict__ g,
    const float* __restrict__ b, float* __restrict__ out)
{
  int row  = (blockIdx.x * 256 + threadIdx.x) >> 6;   // token index
  int lane = threadIdx.x & 63;
  if (row >= MTOK) return;
  int bl = row / N_;            // b*L + l
  int l  = bl & (L_ - 1);
  const float* xr = x + (size_t)row * C_;
  float x0 = xr[lane], x1 = xr[lane + 64];
  int c0 = lane, c1 = lane + 64;
  const float LOG1E4 = 9.210340371976184f;
  float e0 = expf(LOG1E4 * (-2.0f * (float)c0 / 128.0f));
  float e1 = expf(LOG1E4 * (-2.0f * (float)c1 / 128.0f));
  float a0 = (float)l * e0, a1 = (float)l * e1;
  float pe0 = (c0 & 1) ? cosf(a0) : sinf(a0);
  float pe1 = (c1 & 1) ? cosf(a1) : sinf(a1);
  float t0 = x0 + pe0, t1 = x1 + pe1;
  float mean = wave_sum(t0 + t1) * (1.0f/128.0f);
  float d0 = t0 - mean, d1 = t1 - mean;
  float var = wave_sum(d0*d0 + d1*d1) * (1.0f/128.0f);
  float inv = rsqrtf(var + 1e-5f);
  float* orow = out + (size_t)row * C_;
  orow[c0] = x0 + d0 * inv * g[c0] + b[c0];
  orow[c1] = x1 + d1 * inv * g[c1] + b[c1];
}

// ---------------- LayerNorm over C=128, wave per row; fp32 out + optional bf16 out
template<bool WB>
__global__ __launch_bounds__(256) void ln_kernel(
    const float* __restrict__ in, const float* __restrict__ g,
    const float* __restrict__ b, float* __restrict__ outf,
    __bf16* __restrict__ outb)
{
  int row  = (blockIdx.x * 256 + threadIdx.x) >> 6;
  int lane = threadIdx.x & 63;
  if (row >= MTOK) return;
  const float* ir = in + (size_t)row * C_;
  float t0 = ir[lane], t1 = ir[lane + 64];
  float mean = wave_sum(t0 + t1) * (1.0f/128.0f);
  float d0 = t0 - mean, d1 = t1 - mean;
  float var = wave_sum(d0*d0 + d1*d1) * (1.0f/128.0f);
  float inv = rsqrtf(var + 1e-5f);
  float v0 = d0 * inv * g[lane]      + b[lane];
  float v1 = d1 * inv * g[lane + 64] + b[lane + 64];
  float* orow = outf + (size_t)row * C_;
  orow[lane]      = v0;
  orow[lane + 64] = v1;
  if (WB) {
    __bf16* brow = outb + (size_t)row * C_;
    brow[lane]      = (__bf16)v0;
    brow[lane + 64] = (__bf16)v1;
  }
}

// ---------------- weight conversion fp32 -> bf16 arena ----------------
#define WSEG 98304      // NL*H*DK*C = NL*128*128
#define WSEG_FF 393216  // NL*512*128
__global__ __launch_bounds__(256) void wconv_kernel(
    const float* __restrict__ Wq, const float* __restrict__ Wk,
    const float* __restrict__ Wv, const float* __restrict__ Wo,
    const float* __restrict__ W1, const float* __restrict__ W2,
    __bf16* __restrict__ dst)
{
  int i = blockIdx.x * 256 + threadIdx.x;
  float v;
  if      (i <   WSEG) v = Wq[i];
  else if (i < 2*WSEG) v = Wk[i -   WSEG];
  else if (i < 3*WSEG) v = Wv[i - 2*WSEG];
  else if (i < 4*WSEG) v = Wo[i - 3*WSEG];
  else if (i < 4*WSEG + WSEG_FF) v = W1[i - 4*WSEG];
  else v = W2[i - 4*WSEG - WSEG_FF];
  dst[i] = (__bf16)v;
}

// ---------------- bf16 MFMA GEMM -------------------------------------------------
// C[m,n] = sum_k A[m,k]*Bw[n,k], A [M,K] bf16 row-major, Bw [Ntot,K] bf16 row-major.
// Tile 128x128, K staged in 128-chunks. 256 thr = 4 waves (2x2), wave tile 64x64.
// LDS layout: row-major [128][128] bf16 with 16B-chunk XOR swizzle c ^= (row&7),
// achieved via inverse-swizzled global source into linear global_load_lds dest.
// EPI: 0=+bias, 1=mish(+bias), 2=+bias+res.  OUTBF: write bf16 else fp32.
template<int EPI, bool OUTBF>
__global__ __launch_bounds__(256) void mgemm_kernel(
    const __bf16* __restrict__ A, const __bf16* __restrict__ Bw,
    const float* __restrict__ bias, const float* __restrict__ res,
    void* __restrict__ Cout, int K, int Ntot)
{
  __shared__ __align__(16) char smem[2 * 128 * 256];   // A tile + B tile, 64 KiB
  char* sA = smem;
  char* sB = smem + 128 * 256;

  const int tid  = threadIdx.x;
  const int lane = tid & 63;
  const int wv   = tid >> 6;      // wave 0..3
  const int l15  = lane & 15;
  const int lh   = lane >> 4;     // 0..3
  const int wm   = wv >> 1;       // 0..1
  const int wn   = wv & 1;        // 0..1
  const int bm   = blockIdx.x * 128;
  const int bn   = blockIdx.y * 128;

  f32x4 acc[4][4] = {};

  for (int k0 = 0; k0 < K; k0 += 128) {
    // ---- stage A and B tiles: 2048 chunks of 16B each, 8 per thread per tile ----
#pragma unroll
    for (int i = 0; i < 8; ++i) {
      int id  = i * 256 + tid;        // linear chunk id
      int row = id >> 4, c = id & 15;
      int cs  = c ^ (row & 7);        // inverse swizzle on the SOURCE
      const char* g = (const char*)(A + (size_t)(bm + row) * K + k0) + cs * 16;
      __builtin_amdgcn_global_load_lds((const unsigned int*)g,
          (unsigned int*)(sA + (size_t)(i * 256 + wv * 64) * 16), 16, 0, 0);
    }
#pragma unroll
    for (int i = 0; i < 8; ++i) {
      int id  = i * 256 + tid;
      int row = id >> 4, c = id & 15;
      int cs  = c ^ (row & 7);
      const char* g = (const char*)(Bw + (size_t)(bn + row) * K + k0) + cs * 16;
      __builtin_amdgcn_global_load_lds((const unsigned int*)g,
          (unsigned int*)(sB + (size_t)(i * 256 + wv * 64) * 16), 16, 0, 0);
    }
    __syncthreads();

    // ---- MFMA over the 128-K chunk: 4 ksteps of 32 ----
#pragma unroll
    for (int kk = 0; kk < 4; ++kk) {
      bf16x8 af[4], bfr[4];
#pragma unroll
      for (int mi = 0; mi < 4; ++mi) {
        int row = wm * 64 + mi * 16 + l15;
        int cs  = (kk * 4 + lh) ^ (row & 7);   // swizzled read
        af[mi] = *(const bf16x8*)(sA + row * 256 + cs * 16);
      }
#pragma unroll
      for (int ni = 0; ni < 4; ++ni) {
        int row = wn * 64 + ni * 16 + l15;
        int cs  = (kk * 4 + lh) ^ (row & 7);
        bfr[ni] = *(const bf16x8*)(sB + row * 256 + cs * 16);
      }
#pragma unroll
      for (int mi = 0; mi < 4; ++mi)
#pragma unroll
        for (int ni = 0; ni < 4; ++ni)
          acc[mi][ni] = __builtin_amdgcn_mfma_f32_16x16x32_bf16(
              af[mi], bfr[ni], acc[mi][ni], 0, 0, 0);
    }
    __syncthreads();
  }

  // ---- epilogue: C/D layout col=lane&15, row=(lane>>4)*4+reg ----
#pragma unroll
  for (int ni = 0; ni < 4; ++ni) {
    int col = bn + wn * 64 + ni * 16 + l15;
    float bc = bias[col];
#pragma unroll
    for (int mi = 0; mi < 4; ++mi) {
      int rbase = bm + wm * 64 + mi * 16 + lh * 4;
#pragma unroll
      for (int r = 0; r < 4; ++r) {
        float v = acc[mi][ni][r] + bc;
        if (EPI == 1) v = mishf(v);
        size_t idx = (size_t)(rbase + r) * Ntot + col;
        if (EPI == 2) v += res[idx];
        if (OUTBF) ((__bf16*)Cout)[idx] = (__bf16)v;
        else       ((float*)Cout)[idx]  = v;
      }
    }
  }
}

// ---------------- attention over nodes, block per (b,l), scatter-scrambled out ---
__global__ __launch_bounds__(256) void attn_kernel(
    const __bf16* __restrict__ q, const __bf16* __restrict__ k,
    const __bf16* __restrict__ v, __bf16* __restrict__ out)
{
  __shared__ float Ks[N_ * C_];
  __shared__ float Vs[N_ * C_];
  int bl = blockIdx.x;            // b*L + l
  int b  = bl >> 8;
  int l  = bl & (L_ - 1);
  size_t mb = (size_t)bl * N_;    // base token
  for (int i = threadIdx.x; i < N_ * C_; i += 256) {
    Ks[i] = (float)k[mb * C_ + i];
    Vs[i] = (float)v[mb * C_ + i];
  }
  __syncthreads();
  int h  = threadIdx.x >> 5;      // 0..7
  int nq = threadIdx.x & 31;
  if (nq >= N_) return;
  float qr[DK_];
  const __bf16* qp = q + (mb + nq) * C_ + h * DK_;
#pragma unroll
  for (int d = 0; d < DK_; ++d) qr[d] = (float)qp[d];
  float sc[N_];
#pragma unroll
  for (int m = 0; m < N_; ++m) {
    float s = 0.0f;
#pragma unroll
    for (int d = 0; d < DK_; ++d) s = fmaf(qr[d], Ks[m*C_ + h*DK_ + d], s);
    sc[m] = s * 0.25f;            // 1/sqrt(16)
  }
  float mx = -1e30f;
#pragma unroll
  for (int m = 0; m < N_; ++m) mx = fmaxf(mx, sc[m]);
  float sum = 0.0f;
#pragma unroll
  for (int m = 0; m < N_; ++m) { sc[m] = expf(sc[m] - mx); sum += sc[m]; }
  float rs = 1.0f / sum;
  float o[DK_];
#pragma unroll
  for (int d = 0; d < DK_; ++d) o[d] = 0.0f;
#pragma unroll
  for (int m = 0; m < N_; ++m)
#pragma unroll
    for (int d = 0; d < DK_; ++d) o[d] = fmaf(sc[m], Vs[m*C_ + h*DK_ + d], o[d]);
  // scramble scatter: flat = n*L + l -> (l2, n2)
  int flat = nq * L_ + l;
  int l2 = flat / N_;
  int n2 = flat - l2 * N_;
  __bf16* op = out + ((size_t)((b * L_ + l2) * N_ + n2)) * C_ + h * DK_;
#pragma unroll
  for (int d = 0; d < DK_; ++d) op[d] = (__bf16)(o[d] * rs);
}

extern "C" void kernel_launch(void* const* d_in, const int* in_sizes, int n_in,
                              void* d_out, int out_size, void* d_ws, size_t ws_size,
                              hipStream_t stream) {
  const float* x    = (const float*)d_in[0];
  const float* Wq   = (const float*)d_in[1];
  const float* bq   = (const float*)d_in[2];
  const float* Wk   = (const float*)d_in[3];
  const float* bk   = (const float*)d_in[4];
  const float* Wv   = (const float*)d_in[5];
  const float* bv   = (const float*)d_in[6];
  const float* Wo   = (const float*)d_in[7];
  const float* bo   = (const float*)d_in[8];
  const float* W1   = (const float*)d_in[9];
  const float* bf1  = (const float*)d_in[10];
  const float* W2   = (const float*)d_in[11];
  const float* bf2  = (const float*)d_in[12];
  const float* ln1g = (const float*)d_in[13];
  const float* ln1b = (const float*)d_in[14];
  const float* lnAg = (const float*)d_in[15];
  const float* lnAb = (const float*)d_in[16];
  const float* lnFg = (const float*)d_in[17];
  const float* lnFb = (const float*)d_in[18];
  const float* peg  = (const float*)d_in[19];
  const float* peb  = (const float*)d_in[20];

  float* out = (float*)d_out;
  char*  ws  = (char*)d_ws;
  const size_t U = (size_t)MTOK * C_;   // 5,767,168 elements

  // ws layout (bytes)
  __bf16* wbf  = (__bf16*)ws;                          // 2,359,296 B weight arena
  float*  yf   = (float*)(ws + 2359296);               // U*4: LN out fp32 / residual base
  float*  s2   = (float*)(ws + 2359296 + U*4);         // U*4: gemm fp32 out
  __bf16* yb   = (__bf16*)(ws + 2359296 + U*8);        // U*2: LN out bf16
  __bf16* qb   = (__bf16*)(ws + 2359296 + U*10);       // U*2 each: Q,K,V,attn-out
  __bf16* kb   = qb + U;
  __bf16* vb   = kb + U;
  __bf16* sb   = vb + U;
  __bf16* mid  = qb;                                   // aliases q/k/v/sb: M*512 bf16

  dim3 blk(256);
  const int lnGrid = MTOK / 4;          // 11264 blocks, 4 rows each
  dim3 g128(MTOK/128, 1);               // N=128 gemms
  dim3 g512(MTOK/128, 4);               // FF1 gemm, N=512

  wconv_kernel<<<(4*WSEG + 2*WSEG_FF)/256, blk, 0, stream>>>(Wq, Wk, Wv, Wo, W1, W2, wbf);
  pe_kernel<<<lnGrid, blk, 0, stream>>>(x, peg, peb, out);

  for (int li = 0; li < NL_; ++li) {
    const __bf16* wq_b = wbf + (size_t)li * 16384;
    const __bf16* wk_b = wbf + WSEG   + (size_t)li * 16384;
    const __bf16* wv_b = wbf + 2*WSEG + (size_t)li * 16384;
    const __bf16* wo_b = wbf + 3*WSEG + (size_t)li * 16384;
    const __bf16* w1_b = wbf + 4*WSEG + (size_t)li * 65536;
    const __bf16* w2_b = wbf + 4*WSEG + WSEG_FF + (size_t)li * 65536;
    const float* bq_l = bq + (size_t)li * 128;
    const float* bk_l = bk + (size_t)li * 128;
    const float* bv_l = bv + (size_t)li * 128;
    const float* bo_l = bo + (size_t)li * 128;
    const float* b1_l = bf1 + (size_t)li * 512;
    const float* b2_l = bf2 + (size_t)li * 128;
    const float* g1 = ln1g + (size_t)li * C_; const float* bb1 = ln1b + (size_t)li * C_;
    const float* gA = lnAg + (size_t)li * C_; const float* bA  = lnAb + (size_t)li * C_;
    const float* gF = lnFg + (size_t)li * C_; const float* bF  = lnFb + (size_t)li * C_;

    // y = LN1(h): fp32 (residual base) + bf16 (gemm A)
    ln_kernel<true><<<lnGrid, blk, 0, stream>>>(out, g1, bb1, yf, yb);

    // Q,K,V = y @ W^T + b  (bf16 out)
    mgemm_kernel<0,true><<<g128, blk, 0, stream>>>(yb, wq_b, bq_l, nullptr, qb, 128, 128);
    mgemm_kernel<0,true><<<g128, blk, 0, stream>>>(yb, wk_b, bk_l, nullptr, kb, 128, 128);
    mgemm_kernel<0,true><<<g128, blk, 0, stream>>>(yb, wv_b, bv_l, nullptr, vb, 128, 128);

    // attention + head scramble -> sb (bf16)
    attn_kernel<<<B_*L_, blk, 0, stream>>>(qb, kb, vb, sb);

    // s2 = y + sb @ Wo^T + bo (fp32)
    mgemm_kernel<2,false><<<g128, blk, 0, stream>>>(sb, wo_b, bo_l, yf, s2, 128, 128);
    // z = LN_A(s2): fp32 -> yf (FF residual base), bf16 -> yb
    ln_kernel<true><<<lnGrid, blk, 0, stream>>>(s2, gA, bA, yf, yb);

    // FF block #1
    mgemm_kernel<1,true ><<<g512, blk, 0, stream>>>(yb, w1_b, b1_l, nullptr, mid, 128, 512);
    mgemm_kernel<2,false><<<g128, blk, 0, stream>>>(mid, w2_b, b2_l, yf, s2, 512, 128);
    ln_kernel<true><<<lnGrid, blk, 0, stream>>>(s2, gF, bF, yf, yb);

    // FF block #2
    mgemm_kernel<1,true ><<<g512, blk, 0, stream>>>(yb, w1_b, b1_l, nullptr, mid, 128, 512);
    mgemm_kernel<2,false><<<g128, blk, 0, stream>>>(mid, w2_b, b2_l, yf, s2, 512, 128);
    ln_kernel<false><<<lnGrid, blk, 0, stream>>>(s2, gF, bF, out, nullptr);
  }
  (void)in_sizes; (void)n_in; (void)out_size; (void)ws_size;
}

// Round 3
// 1185.027 us; speedup vs baseline: 4.6553x; 2.5637x over previous
//
#include <hip/hip_runtime.h>
#include <math.h>

#define B_ 8
#define L_ 256
#define N_ 22
#define C_ 128
#define H_ 8
#define DK_ 16
#define DFF_ 512
#define NL_ 6
#define MTOK (B_*L_*N_)   // 45056

typedef __bf16 bf16x8 __attribute__((ext_vector_type(8)));
typedef float  f32x4  __attribute__((ext_vector_type(4)));

__device__ __forceinline__ float wave_sum(float v){
#pragma unroll
  for (int i = 32; i >= 1; i >>= 1) v += __shfl_xor(v, i, 64);
  return v;
}

// fast mish: x * tanh(softplus(x)) == x*(t^2+2t)/(t^2+2t+2), t=e^x
__device__ __forceinline__ float mishf(float x){
  float t = __expf(fminf(x, 20.0f));
  float num = t * (t + 2.0f);
  return x * num / (num + 2.0f);
}

// ---------------- positional-encoder kernel: out = x + LN(x + pe) ----------------
__global__ __launch_bounds__(256) void pe_kernel(
    const float* __restrict__ x, const float* __restrict__ g,
    const float* __restrict__ b, float* __restrict__ out)
{
  int row  = (blockIdx.x * 256 + threadIdx.x) >> 6;   // token index
  int lane = threadIdx.x & 63;
  if (row >= MTOK) return;
  int bl = row / N_;            // b*L + l
  int l  = bl & (L_ - 1);
  const float* xr = x + (size_t)row * C_;
  float x0 = xr[lane], x1 = xr[lane + 64];
  int c0 = lane, c1 = lane + 64;
  const float LOG1E4 = 9.210340371976184f;
  float e0 = __expf(LOG1E4 * (-2.0f * (float)c0 / 128.0f));
  float e1 = __expf(LOG1E4 * (-2.0f * (float)c1 / 128.0f));
  float a0 = (float)l * e0, a1 = (float)l * e1;
  float pe0 = (c0 & 1) ? cosf(a0) : sinf(a0);
  float pe1 = (c1 & 1) ? cosf(a1) : sinf(a1);
  float t0 = x0 + pe0, t1 = x1 + pe1;
  float mean = wave_sum(t0 + t1) * (1.0f/128.0f);
  float d0 = t0 - mean, d1 = t1 - mean;
  float var = wave_sum(d0*d0 + d1*d1) * (1.0f/128.0f);
  float inv = rsqrtf(var + 1e-5f);
  float* orow = out + (size_t)row * C_;
  orow[c0] = x0 + d0 * inv * g[c0] + b[c0];
  orow[c1] = x1 + d1 * inv * g[c1] + b[c1];
}

// ---------------- standalone LN (layer-0 entry only): fp32 + bf16 out ----------
__global__ __launch_bounds__(256) void ln_kernel(
    const float* __restrict__ in, const float* __restrict__ g,
    const float* __restrict__ b, float* __restrict__ outf,
    __bf16* __restrict__ outb)
{
  int row  = (blockIdx.x * 256 + threadIdx.x) >> 6;
  int lane = threadIdx.x & 63;
  if (row >= MTOK) return;
  const float* ir = in + (size_t)row * C_;
  float t0 = ir[lane], t1 = ir[lane + 64];
  float mean = wave_sum(t0 + t1) * (1.0f/128.0f);
  float d0 = t0 - mean, d1 = t1 - mean;
  float var = wave_sum(d0*d0 + d1*d1) * (1.0f/128.0f);
  float inv = rsqrtf(var + 1e-5f);
  float v0 = d0 * inv * g[lane]      + b[lane];
  float v1 = d1 * inv * g[lane + 64] + b[lane + 64];
  float* orow = outf + (size_t)row * C_;
  orow[lane]      = v0;
  orow[lane + 64] = v1;
  __bf16* brow = outb + (size_t)row * C_;
  brow[lane]      = (__bf16)v0;
  brow[lane + 64] = (__bf16)v1;
}

// ---------------- weight pack fp32 -> bf16 arena ----------------
// layout (bf16 elements):
//   [0)        QKV: li*49152 + which*16384 + r*128 + c   (which: 0=Q,1=K,2=V)
//   [589824)   Wo : li*16384 + r*128 + c
//   [688128)   W1 : li*65536 + r*128 + c                 (512x128)
//   [1081344)  W2 : li*65536 + r*512 + c                 (128x512)
//   total 1474560
__global__ __launch_bounds__(256) void wpack_kernel(
    const float* __restrict__ Wq, const float* __restrict__ Wk,
    const float* __restrict__ Wv, const float* __restrict__ Wo,
    const float* __restrict__ W1, const float* __restrict__ W2,
    __bf16* __restrict__ dst)
{
  int i = blockIdx.x * 256 + threadIdx.x;
  float v;
  if (i < 589824) {
    int li = i / 49152, rem = i % 49152;
    int which = rem / 16384, idx = rem % 16384;
    const float* W = which == 0 ? Wq : which == 1 ? Wk : Wv;
    v = W[li * 16384 + idx];
  } else if (i < 688128) v = Wo[i - 589824];
  else if (i < 1081344)  v = W1[i - 688128];
  else                   v = W2[i - 1081344];
  dst[i] = (__bf16)v;
}

// pack QKV biases: [NL][384] fp32
__global__ __launch_bounds__(256) void bpack_kernel(
    const float* __restrict__ bq, const float* __restrict__ bk,
    const float* __restrict__ bv, float* __restrict__ dst)
{
  int i = blockIdx.x * 256 + threadIdx.x;   // < NL*384
  int li = i / 384, p = i % 384;
  float v = p < 128 ? bq[li*128 + p] : p < 256 ? bk[li*128 + p - 128] : bv[li*128 + p - 256];
  dst[i] = v;
}

// ---------------- bf16 MFMA GEMM with fused epilogues ----------------------------
// C[m,n] = sum_k A[m,k]*Bw[n,k]. Tile 128x128, 4 waves (2x2), wave tile 64x64.
// LDS: [128 rows][16 chunks of 16B] with chunk XOR swizzle c ^= (row&7).
// EPI: 0 = +bias; 1 = mish(+bias).   (only used when LN==0)
// LN:  0 = none (write bf16 to outb)
//      1 = v=acc+bias+res; y=LN(v;g1,b1); outf=y (fp32, may alias res), outb=bf16(y)
//      2 = v=acc+bias+res; h=LN(v;g1,b1); hout=h; if g2: y=LN(h;g2,b2)->outf,outb
template<int EPI, int LN>
__global__ __launch_bounds__(256) void mgemm2(
    const __bf16* __restrict__ A, const __bf16* __restrict__ Bw,
    const float* __restrict__ bias, const float* __restrict__ res,
    __bf16* __restrict__ outb, float* __restrict__ outf,
    float* __restrict__ hout,
    const float* __restrict__ g1, const float* __restrict__ b1v,
    const float* __restrict__ g2, const float* __restrict__ b2v,
    int K, int Ntot)
{
  __shared__ __align__(16) char smem[2 * 128 * 256];   // A tile + B tile, 64 KiB
  char* sA = smem;
  char* sB = smem + 128 * 256;

  const int tid  = threadIdx.x;
  const int lane = tid & 63;
  const int wv   = tid >> 6;      // wave 0..3
  const int l15  = lane & 15;
  const int lh   = lane >> 4;     // 0..3
  const int wm   = wv >> 1;       // 0..1
  const int wn   = wv & 1;        // 0..1
  const int bm   = blockIdx.x * 128;
  const int bn   = blockIdx.y * 128;

  f32x4 acc[4][4] = {};

  for (int k0 = 0; k0 < K; k0 += 128) {
#pragma unroll
    for (int i = 0; i < 8; ++i) {
      int id  = i * 256 + tid;
      int row = id >> 4, c = id & 15;
      int cs  = c ^ (row & 7);
      const char* g = (const char*)(A + (size_t)(bm + row) * K + k0) + cs * 16;
      __builtin_amdgcn_global_load_lds((const unsigned int*)g,
          (unsigned int*)(sA + (size_t)(i * 256 + wv * 64) * 16), 16, 0, 0);
    }
#pragma unroll
    for (int i = 0; i < 8; ++i) {
      int id  = i * 256 + tid;
      int row = id >> 4, c = id & 15;
      int cs  = c ^ (row & 7);
      const char* g = (const char*)(Bw + (size_t)(bn + row) * K + k0) + cs * 16;
      __builtin_amdgcn_global_load_lds((const unsigned int*)g,
          (unsigned int*)(sB + (size_t)(i * 256 + wv * 64) * 16), 16, 0, 0);
    }
    __syncthreads();

#pragma unroll
    for (int kk = 0; kk < 4; ++kk) {
      bf16x8 af[4], bfr[4];
#pragma unroll
      for (int mi = 0; mi < 4; ++mi) {
        int row = wm * 64 + mi * 16 + l15;
        int cs  = (kk * 4 + lh) ^ (row & 7);
        af[mi] = *(const bf16x8*)(sA + row * 256 + cs * 16);
      }
#pragma unroll
      for (int ni = 0; ni < 4; ++ni) {
        int row = wn * 64 + ni * 16 + l15;
        int cs  = (kk * 4 + lh) ^ (row & 7);
        bfr[ni] = *(const bf16x8*)(sB + row * 256 + cs * 16);
      }
#pragma unroll
      for (int mi = 0; mi < 4; ++mi)
#pragma unroll
        for (int ni = 0; ni < 4; ++ni)
          acc[mi][ni] = __builtin_amdgcn_mfma_f32_16x16x32_bf16(
              af[mi], bfr[ni], acc[mi][ni], 0, 0, 0);
    }
    __syncthreads();
  }

  // ---- epilogue: C/D layout col=lane&15, row=(lane>>4)*4+reg ----
  if (LN == 0) {
#pragma unroll
    for (int ni = 0; ni < 4; ++ni) {
      int col = bn + wn * 64 + ni * 16 + l15;
      float bc = bias[col];
#pragma unroll
      for (int mi = 0; mi < 4; ++mi) {
        int rbase = bm + wm * 64 + mi * 16 + lh * 4;
#pragma unroll
        for (int r = 0; r < 4; ++r) {
          float v = acc[mi][ni][r] + bc;
          if (EPI == 1) v = mishf(v);
          outb[(size_t)(rbase + r) * Ntot + col] = (__bf16)v;
        }
      }
    }
  } else {
    // LN epilogue (Ntot == 128, bn == 0): block owns full rows.
    float* sArr  = (float*)smem;          // [128][2]
    float* s2Arr = sArr + 256;            // [128][2]
    float* mArr  = s2Arr + 256;           // [128]
    float* iArr  = mArr + 128;            // [128]

    // fold bias + residual into acc -> v
#pragma unroll
    for (int ni = 0; ni < 4; ++ni) {
      int col = wn * 64 + ni * 16 + l15;
      float bc = bias[col];
#pragma unroll
      for (int mi = 0; mi < 4; ++mi) {
        int Rl = wm * 64 + mi * 16 + lh * 4;
#pragma unroll
        for (int r = 0; r < 4; ++r)
          acc[mi][ni][r] += bc + res[(size_t)(bm + Rl + r) * 128 + col];
      }
    }
    // row sums (first LN)
#pragma unroll
    for (int mi = 0; mi < 4; ++mi)
#pragma unroll
      for (int r = 0; r < 4; ++r) {
        int Rl = wm * 64 + mi * 16 + lh * 4 + r;
        float s = acc[mi][0][r] + acc[mi][1][r] + acc[mi][2][r] + acc[mi][3][r];
        float q = acc[mi][0][r]*acc[mi][0][r] + acc[mi][1][r]*acc[mi][1][r]
                + acc[mi][2][r]*acc[mi][2][r] + acc[mi][3][r]*acc[mi][3][r];
#pragma unroll
        for (int msk = 1; msk <= 8; msk <<= 1) {
          s += __shfl_xor(s, msk, 64);
          q += __shfl_xor(q, msk, 64);
        }
        if (l15 == 0) { sArr[Rl*2 + wn] = s; s2Arr[Rl*2 + wn] = q; }
      }
    __syncthreads();
    if (tid < 128) {
      float m  = (sArr[tid*2] + sArr[tid*2+1]) * (1.0f/128.0f);
      float vv = (s2Arr[tid*2] + s2Arr[tid*2+1]) * (1.0f/128.0f) - m*m;
      mArr[tid] = m; iArr[tid] = rsqrtf(vv + 1e-5f);
    }
    __syncthreads();

    if (LN == 1) {
#pragma unroll
      for (int mi = 0; mi < 4; ++mi)
#pragma unroll
        for (int r = 0; r < 4; ++r) {
          int Rl = wm * 64 + mi * 16 + lh * 4 + r;
          float m = mArr[Rl], inv = iArr[Rl];
#pragma unroll
          for (int ni = 0; ni < 4; ++ni) {
            int col = wn * 64 + ni * 16 + l15;
            float y = (acc[mi][ni][r] - m) * inv * g1[col] + b1v[col];
            size_t idx = (size_t)(bm + Rl) * 128 + col;
            outf[idx] = y;
            outb[idx] = (__bf16)y;
          }
        }
    } else {
      // LN==2: h = LN(v), write hout; then optional second LN
#pragma unroll
      for (int mi = 0; mi < 4; ++mi)
#pragma unroll
        for (int r = 0; r < 4; ++r) {
          int Rl = wm * 64 + mi * 16 + lh * 4 + r;
          float m = mArr[Rl], inv = iArr[Rl];
#pragma unroll
          for (int ni = 0; ni < 4; ++ni) {
            int col = wn * 64 + ni * 16 + l15;
            float h = (acc[mi][ni][r] - m) * inv * g1[col] + b1v[col];
            acc[mi][ni][r] = h;
            hout[(size_t)(bm + Rl) * 128 + col] = h;
          }
        }
      if (g2 != nullptr) {
#pragma unroll
        for (int mi = 0; mi < 4; ++mi)
#pragma unroll
          for (int r = 0; r < 4; ++r) {
            int Rl = wm * 64 + mi * 16 + lh * 4 + r;
            float s = acc[mi][0][r] + acc[mi][1][r] + acc[mi][2][r] + acc[mi][3][r];
            float q = acc[mi][0][r]*acc[mi][0][r] + acc[mi][1][r]*acc[mi][1][r]
                    + acc[mi][2][r]*acc[mi][2][r] + acc[mi][3][r]*acc[mi][3][r];
#pragma unroll
            for (int msk = 1; msk <= 8; msk <<= 1) {
              s += __shfl_xor(s, msk, 64);
              q += __shfl_xor(q, msk, 64);
            }
            if (l15 == 0) { sArr[Rl*2 + wn] = s; s2Arr[Rl*2 + wn] = q; }
          }
        __syncthreads();
        if (tid < 128) {
          float m  = (sArr[tid*2] + sArr[tid*2+1]) * (1.0f/128.0f);
          float vv = (s2Arr[tid*2] + s2Arr[tid*2+1]) * (1.0f/128.0f) - m*m;
          mArr[tid] = m; iArr[tid] = rsqrtf(vv + 1e-5f);
        }
        __syncthreads();
#pragma unroll
        for (int mi = 0; mi < 4; ++mi)
#pragma unroll
          for (int r = 0; r < 4; ++r) {
            int Rl = wm * 64 + mi * 16 + lh * 4 + r;
            float m = mArr[Rl], inv = iArr[Rl];
#pragma unroll
            for (int ni = 0; ni < 4; ++ni) {
              int col = wn * 64 + ni * 16 + l15;
              float y = (acc[mi][ni][r] - m) * inv * g2[col] + b2v[col];
              size_t idx = (size_t)(bm + Rl) * 128 + col;
              outf[idx] = y;
              outb[idx] = (__bf16)y;
            }
          }
      }
    }
  }
}

// ---------------- attention over nodes, block per (b,l), scatter-scrambled out ---
// Q,K,V packed in one buffer, stride 384: q at +0, k at +128, v at +256.
__global__ __launch_bounds__(256) void attn_kernel(
    const __bf16* __restrict__ qkv, __bf16* __restrict__ out)
{
  __shared__ float Ks[N_ * C_];
  __shared__ float Vs[N_ * C_];
  int bl = blockIdx.x;            // b*L + l
  int b  = bl >> 8;
  int l  = bl & (L_ - 1);
  size_t mb = (size_t)bl * N_;    // base token
  for (int i = threadIdx.x; i < N_ * C_; i += 256) {
    int row = i >> 7, c = i & 127;
    Ks[i] = (float)qkv[(mb + row) * 384 + 128 + c];
    Vs[i] = (float)qkv[(mb + row) * 384 + 256 + c];
  }
  __syncthreads();
  int h  = threadIdx.x >> 5;      // 0..7
  int nq = threadIdx.x & 31;
  if (nq >= N_) return;
  float qr[DK_];
  const __bf16* qp = qkv + (mb + nq) * 384 + h * DK_;
#pragma unroll
  for (int d = 0; d < DK_; ++d) qr[d] = (float)qp[d];
  float sc[N_];
#pragma unroll
  for (int m = 0; m < N_; ++m) {
    float s = 0.0f;
#pragma unroll
    for (int d = 0; d < DK_; ++d) s = fmaf(qr[d], Ks[m*C_ + h*DK_ + d], s);
    sc[m] = s * 0.25f;            // 1/sqrt(16)
  }
  float mx = -1e30f;
#pragma unroll
  for (int m = 0; m < N_; ++m) mx = fmaxf(mx, sc[m]);
  float sum = 0.0f;
#pragma unroll
  for (int m = 0; m < N_; ++m) { sc[m] = __expf(sc[m] - mx); sum += sc[m]; }
  float rs = 1.0f / sum;
  float o[DK_];
#pragma unroll
  for (int d = 0; d < DK_; ++d) o[d] = 0.0f;
#pragma unroll
  for (int m = 0; m < N_; ++m)
#pragma unroll
    for (int d = 0; d < DK_; ++d) o[d] = fmaf(sc[m], Vs[m*C_ + h*DK_ + d], o[d]);
  int flat = nq * L_ + l;
  int l2 = flat / N_;
  int n2 = flat - l2 * N_;
  __bf16* op = out + ((size_t)((b * L_ + l2) * N_ + n2)) * C_ + h * DK_;
#pragma unroll
  for (int d = 0; d < DK_; ++d) op[d] = (__bf16)(o[d] * rs);
}

extern "C" void kernel_launch(void* const* d_in, const int* in_sizes, int n_in,
                              void* d_out, int out_size, void* d_ws, size_t ws_size,
                              hipStream_t stream) {
  const float* x    = (const float*)d_in[0];
  const float* Wq   = (const float*)d_in[1];
  const float* bq   = (const float*)d_in[2];
  const float* Wk   = (const float*)d_in[3];
  const float* bk   = (const float*)d_in[4];
  const float* Wv   = (const float*)d_in[5];
  const float* bv   = (const float*)d_in[6];
  const float* Wo   = (const float*)d_in[7];
  const float* bo   = (const float*)d_in[8];
  const float* W1   = (const float*)d_in[9];
  const float* bf1  = (const float*)d_in[10];
  const float* W2   = (const float*)d_in[11];
  const float* bf2  = (const float*)d_in[12];
  const float* ln1g = (const float*)d_in[13];
  const float* ln1b = (const float*)d_in[14];
  const float* lnAg = (const float*)d_in[15];
  const float* lnAb = (const float*)d_in[16];
  const float* lnFg = (const float*)d_in[17];
  const float* lnFb = (const float*)d_in[18];
  const float* peg  = (const float*)d_in[19];
  const float* peb  = (const float*)d_in[20];

  float* out = (float*)d_out;
  char*  ws  = (char*)d_ws;
  const size_t U = (size_t)MTOK * C_;   // 5,767,168 elements

  // ws layout (bytes), all 256B-aligned
  __bf16* wbf   = (__bf16*)ws;                         // 2,949,120 B weight arena
  float*  bqkv  = (float*)(ws + 2949120);              // NL*384*4 = 9216 B
  float*  yf    = (float*)(ws + 2958592);              // U*4 fp32 residual/LN base
  __bf16* yb    = (__bf16*)(ws + 2958592 + U*4);       // U*2 bf16 LN out (gemm A)
  __bf16* qkvb  = (__bf16*)(ws + 2958592 + U*6);       // 3U*2 packed QKV
  __bf16* sb    = (__bf16*)(ws + 2958592 + U*12);      // U*2 scrambled attn out
  __bf16* mid   = (__bf16*)(ws + 2958592 + U*14);      // 4U*2 FF hidden

  dim3 blk(256);
  const int lnGrid = MTOK / 4;
  dim3 gqkv(MTOK/128, 3);
  dim3 g128(MTOK/128, 1);
  dim3 g512(MTOK/128, 4);

  wpack_kernel<<<1474560/256, blk, 0, stream>>>(Wq, Wk, Wv, Wo, W1, W2, wbf);
  bpack_kernel<<<NL_*384/256, blk, 0, stream>>>(bq, bk, bv, bqkv);
  pe_kernel<<<lnGrid, blk, 0, stream>>>(x, peg, peb, out);
  // layer-0 entry LN1
  ln_kernel<<<lnGrid, blk, 0, stream>>>(out, ln1g, ln1b, yf, yb);

  for (int li = 0; li < NL_; ++li) {
    const __bf16* wqkv_b = wbf + (size_t)li * 49152;
    const __bf16* wo_b   = wbf + 589824  + (size_t)li * 16384;
    const __bf16* w1_b   = wbf + 688128  + (size_t)li * 65536;
    const __bf16* w2_b   = wbf + 1081344 + (size_t)li * 65536;
    const float* bqkv_l = bqkv + (size_t)li * 384;
    const float* bo_l = bo + (size_t)li * 128;
    const float* b1_l = bf1 + (size_t)li * 512;
    const float* b2_l = bf2 + (size_t)li * 128;
    const float* gA = lnAg + (size_t)li * C_; const float* bA = lnAb + (size_t)li * C_;
    const float* gF = lnFg + (size_t)li * C_; const float* bF = lnFb + (size_t)li * C_;
    const float* g1n = (li < NL_-1) ? ln1g + (size_t)(li+1) * C_ : nullptr;
    const float* b1n = (li < NL_-1) ? ln1b + (size_t)(li+1) * C_ : nullptr;

    // QKV = y @ [Wq;Wk;Wv]^T + b  (one N=384 gemm)
    mgemm2<0,0><<<gqkv, blk, 0, stream>>>(yb, wqkv_b, bqkv_l, nullptr,
        qkvb, nullptr, nullptr, nullptr, nullptr, nullptr, nullptr, 128, 384);

    // attention + head scramble -> sb
    attn_kernel<<<B_*L_, blk, 0, stream>>>(qkvb, sb);

    // z = LN_A(y + sb@Wo^T + bo): yf/yb updated in place
    mgemm2<0,1><<<g128, blk, 0, stream>>>(sb, wo_b, bo_l, yf,
        yb, yf, nullptr, gA, bA, nullptr, nullptr, 128, 128);

    // FF block #1: mid = mish(z@W1^T+b1); u3 = LN_F(z + mid@W2^T+b2) -> yf/yb
    mgemm2<1,0><<<g512, blk, 0, stream>>>(yb, w1_b, b1_l, nullptr,
        mid, nullptr, nullptr, nullptr, nullptr, nullptr, nullptr, 128, 512);
    mgemm2<0,1><<<g128, blk, 0, stream>>>(mid, w2_b, b2_l, yf,
        yb, yf, nullptr, gF, bF, nullptr, nullptr, 512, 128);

    // FF block #2: h = LN_F(u3 + f(u3)) -> out; y_next = LN1_next(h) -> yf/yb
    mgemm2<1,0><<<g512, blk, 0, stream>>>(yb, w1_b, b1_l, nullptr,
        mid, nullptr, nullptr, nullptr, nullptr, nullptr, nullptr, 128, 512);
    mgemm2<0,2><<<g128, blk, 0, stream>>>(mid, w2_b, b2_l, yf,
        yb, yf, out, gF, bF, g1n, b1n, 512, 128);
  }
  (void)in_sizes; (void)n_in; (void)out_size; (void)ws_size;
}